// Round 1
// baseline (1719.460 us; speedup 1.0000x reference)
//
#include <hip/hip_runtime.h>
#include <math.h>

#define DF 512
#define DH 64
#define DL 16
#define NC 10
#define NF 10
#define KPROP 10

__device__ __forceinline__ float softplus_(float x){
  // jax.nn.softplus = logaddexp(x, 0) = max(x,0) + log1p(exp(-|x|))
  return fmaxf(x, 0.0f) + log1pf(expf(-fabsf(x)));
}

// ---------------- GEMM1: h = relu(x @ W1 + b1) ----------------
#define BM 64
#define BN 64
#define BK 32
__global__ __launch_bounds__(256) void k_gemm1(const float* __restrict__ x,
    const float* __restrict__ W1, const float* __restrict__ b1,
    float* __restrict__ h, int N)
{
  __shared__ float At[BK][BM+4];   // A transposed: At[k][m]
  __shared__ float Bs[BK][BN+4];
  const int tid = threadIdx.x;
  const int tx = tid & 15, ty = tid >> 4;   // 16x16 thread grid, 4x4 microtile
  const int row0 = blockIdx.x * BM;
  float acc[4][4] = {};
  for (int k0 = 0; k0 < DF; k0 += BK) {
    #pragma unroll
    for (int i = 0; i < 2; ++i) {
      int idx = tid + i*256;            // 0..511 float4 slots
      int r  = idx >> 3;                // 8 float4 per 32-wide row
      int kk = (idx & 7) << 2;
      int row = row0 + r;
      float4 va = make_float4(0.f,0.f,0.f,0.f);
      if (row < N) va = *(const float4*)&x[(size_t)row*DF + k0 + kk];
      At[kk+0][r]=va.x; At[kk+1][r]=va.y; At[kk+2][r]=va.z; At[kk+3][r]=va.w;
      int r2 = idx >> 4;                // 16 float4 per 64-wide row
      int c4 = (idx & 15) << 2;
      float4 vb = *(const float4*)&W1[(size_t)(k0+r2)*DH + c4];
      Bs[r2][c4+0]=vb.x; Bs[r2][c4+1]=vb.y; Bs[r2][c4+2]=vb.z; Bs[r2][c4+3]=vb.w;
    }
    __syncthreads();
    #pragma unroll
    for (int kk = 0; kk < BK; ++kk) {
      float4 av = *(const float4*)&At[kk][ty<<2];
      float4 bv = *(const float4*)&Bs[kk][tx<<2];
      float a4[4]={av.x,av.y,av.z,av.w};
      float b4[4]={bv.x,bv.y,bv.z,bv.w};
      #pragma unroll
      for (int i=0;i<4;++i)
        #pragma unroll
        for (int j=0;j<4;++j) acc[i][j] = fmaf(a4[i], b4[j], acc[i][j]);
    }
    __syncthreads();
  }
  #pragma unroll
  for (int i=0;i<4;++i){
    int row = row0 + (ty<<2) + i;
    if (row < N){
      #pragma unroll
      for (int j=0;j<4;++j){
        int col = (tx<<2)+j;
        float v = acc[i][j] + b1[col];
        h[(size_t)row*DH + col] = fmaxf(v, 0.0f);
      }
    }
  }
}

// ------------- z = h@W2 + b2 ; radial flows ; beta_ft -------------
__global__ __launch_bounds__(256) void k_flow(const float* __restrict__ h,
    const float* __restrict__ W2, const float* __restrict__ b2,
    const float* __restrict__ pc, const float* __restrict__ z0g,
    const float* __restrict__ apg, const float* __restrict__ fbg,
    float* __restrict__ x0, int N)
{
  __shared__ float W2s[DH][DL+1];
  __shared__ float z0s[NF][NC][DL];
  __shared__ float alps[NF][NC];
  __shared__ float bhs[NF][NC];
  __shared__ float lpc[NC];
  __shared__ float b2s[DL];
  int tid = threadIdx.x;
  for (int i = tid; i < DH*DL; i += 256) W2s[i>>4][i&15] = W2[i];
  for (int i = tid; i < NF*NC*DL; i += 256) z0s[(i>>4)/NC][(i>>4)%NC][i&15] = z0g[i];
  if (tid < NF*NC){
    int l = tid/NC, c = tid%NC;
    float al = softplus_(apg[tid]);
    alps[l][c] = al;
    bhs[l][c]  = -al + softplus_(fbg[tid]);
  }
  if (tid < NC) lpc[tid] = logf(pc[tid]);
  if (tid < DL) b2s[tid] = b2[tid];
  __syncthreads();
  int n = blockIdx.x*256 + tid;
  if (n >= N) return;

  float z[DL];
  #pragma unroll
  for (int d=0; d<DL; ++d) z[d] = b2s[d];
  const float* hp = h + (size_t)n*DH;
  for (int k=0; k<DH; k+=4){
    float4 hv = *(const float4*)&hp[k];
    float hvv[4] = {hv.x,hv.y,hv.z,hv.w};
    #pragma unroll
    for (int kk=0; kk<4; ++kk)
      #pragma unroll
      for (int d=0; d<DL; ++d) z[d] = fmaf(hvv[kk], W2s[k+kk][d], z[d]);
  }

  const float NEGHALFD_LOG2PI = -14.703016531274762f;  // -8*log(2*pi)
  const float LOGSCALE        =  20.248193975754326f;  //  8*log(4*pi)
  #pragma unroll 1
  for (int c=0; c<NC; ++c){
    float zz[DL];
    #pragma unroll
    for (int d=0; d<DL; ++d) zz[d] = z[d];
    float sld = 0.f;
    #pragma unroll 1
    for (int l=0; l<NF; ++l){
      float al = alps[l][c], bhat = bhs[l][c];
      float dz[DL]; float r2 = 0.f;
      #pragma unroll
      for (int d=0; d<DL; ++d){ float t = zz[d] - z0s[l][c][d]; dz[d]=t; r2 = fmaf(t,t,r2); }
      float r  = sqrtf(r2);
      float hh = 1.0f/(al + r);
      float bh = bhat*hh;
      #pragma unroll
      for (int d=0; d<DL; ++d) zz[d] = fmaf(bh, dz[d], zz[d]);
      sld += 15.0f*log1pf(bh) + log1pf(bh - bhat*r*hh*hh);
    }
    float q2 = 0.f;
    #pragma unroll
    for (int d=0; d<DL; ++d) q2 = fmaf(zz[d], zz[d], q2);
    float v = -0.5f*q2 + NEGHALFD_LOG2PI + sld + lpc[c] + LOGSCALE;
    v = fminf(fmaxf(v, -30.f), 30.f);
    x0[(size_t)n*DL + c] = expf(v);
  }
  #pragma unroll
  for (int c=NC; c<DL; ++c) x0[(size_t)n*DL + c] = 0.f;
}

// ---------------- CSR construction ----------------
__global__ void k_count(const int* __restrict__ dst, int* __restrict__ deg, int E){
  int e = blockIdx.x*256 + threadIdx.x;
  if (e < E) atomicAdd(&deg[dst[e]], 1);
}

__global__ void k_dinv(const int* __restrict__ deg, float* __restrict__ dinv, int N){
  int n = blockIdx.x*256 + threadIdx.x;
  if (n < N) dinv[n] = 1.0f / sqrtf((float)(deg[n] + 1));   // +1 self loop
}

__global__ __launch_bounds__(256) void k_scan_part(const int* __restrict__ deg,
    int* __restrict__ part, int N){
  __shared__ int sd[256];
  int base = blockIdx.x*1024;
  int tid = threadIdx.x;
  int s = 0;
  #pragma unroll
  for (int i=0;i<4;++i){ int idx = base + tid*4 + i; if (idx < N) s += deg[idx]; }
  sd[tid] = s; __syncthreads();
  for (int ofs=128; ofs>0; ofs>>=1){ if (tid<ofs) sd[tid]+=sd[tid+ofs]; __syncthreads(); }
  if (tid==0) part[blockIdx.x] = sd[0];
}

__global__ void k_scan_top(int* part, int nb){
  if (blockIdx.x==0 && threadIdx.x==0){
    int run = 0;
    for (int i=0;i<nb;++i){ int v = part[i]; part[i] = run; run += v; }
  }
}

__global__ __launch_bounds__(256) void k_scan_final(const int* __restrict__ deg,
    const int* __restrict__ part, int* __restrict__ off, int N, int E)
{
  __shared__ int sc[256];
  int base = blockIdx.x*1024;
  int tid = threadIdx.x;
  int v[4]; int s = 0;
  #pragma unroll
  for (int i=0;i<4;++i){ int idx = base + tid*4 + i; v[i] = (idx<N)?deg[idx]:0; s += v[i]; }
  sc[tid] = s; __syncthreads();
  for (int ofs=1; ofs<256; ofs<<=1){
    int t = (tid>=ofs) ? sc[tid-ofs] : 0;
    __syncthreads();
    sc[tid] += t;
    __syncthreads();
  }
  int ex = sc[tid] - s + part[blockIdx.x];
  #pragma unroll
  for (int i=0;i<4;++i){
    int idx = base + tid*4 + i;
    if (idx < N){
      off[idx] = ex;
      if (idx == N-1) off[N] = ex + v[i];
      ex += v[i];
    }
  }
}

__global__ void k_scatter(const int* __restrict__ src, const int* __restrict__ dst,
    const int* __restrict__ off, int* __restrict__ cur, int* __restrict__ csr, int E){
  int e = blockIdx.x*256 + threadIdx.x;
  if (e < E){
    int d = dst[e];
    int p = off[d] + atomicAdd(&cur[d], 1);
    csr[p] = src[e];
  }
}

// canonicalize segment order (sorted by src) -> deterministic fp sums
__global__ void k_sort(int* __restrict__ csr, const int* __restrict__ off, int N){
  int n = blockIdx.x*256 + threadIdx.x;
  if (n >= N) return;
  int s = off[n], e = off[n+1];
  for (int i = s+1; i < e; ++i){
    int key = csr[i];
    int j = i-1;
    while (j >= s && csr[j] > key){ csr[j+1] = csr[j]; --j; }
    csr[j+1] = key;
  }
}

// ---------------- APPNP iteration ----------------
__global__ __launch_bounds__(256) void k_prop(const float* __restrict__ bsrc,
    const float* __restrict__ x0, float* __restrict__ bdst,
    const int* __restrict__ csr, const int* __restrict__ off,
    const float* __restrict__ dinv, int N)
{
  int t = blockIdx.x*256 + threadIdx.x;
  int n = t >> 4, lane = t & 15;
  if (n >= N) return;
  float dn = dinv[n];
  float acc = dn * bsrc[(size_t)n*DL + lane];         // self loop (x dn later)
  int s = off[n], e = off[n+1];
  for (int i = s; i < e; ++i){
    int sc = csr[i];
    acc = fmaf(dinv[sc], bsrc[(size_t)sc*DL + lane], acc);
  }
  float out = fmaf(0.9f, dn*acc, 0.1f*x0[(size_t)n*DL + lane]);
  bdst[(size_t)n*DL + lane] = out;
}

// ---------------- finalize: alpha, soft, argmax ----------------
__global__ void k_final(const float* __restrict__ bsrc, float* __restrict__ out, int N){
  int n = blockIdx.x*256 + threadIdx.x;
  if (n >= N) return;
  float a[NC]; float s = 0.f;
  #pragma unroll
  for (int c=0;c<NC;++c){ a[c] = 1.0f + bsrc[(size_t)n*DL + c]; s += a[c]; }
  float best = -1.0f; int bi = 0;
  #pragma unroll
  for (int c=0;c<NC;++c){
    float so = a[c] / s;
    out[(size_t)N + (size_t)n*NC + c] = so;
    if (so > best){ best = so; bi = c; }
  }
  out[n] = (float)bi;
}

extern "C" void kernel_launch(void* const* d_in, const int* in_sizes, int n_in,
                              void* d_out, int out_size, void* d_ws, size_t ws_size,
                              hipStream_t stream)
{
  const float* x  = (const float*)d_in[0];
  const int*   ei = (const int*)  d_in[1];
  const float* pc = (const float*)d_in[2];
  const float* W1 = (const float*)d_in[3];
  const float* b1 = (const float*)d_in[4];
  const float* W2 = (const float*)d_in[5];
  const float* b2 = (const float*)d_in[6];
  const float* z0 = (const float*)d_in[7];
  const float* ap = (const float*)d_in[8];
  const float* fb = (const float*)d_in[9];
  float* out = (float*)d_out;

  const int N = in_sizes[0] / DF;
  const int E = in_sizes[1] / 2;
  const int* src = ei;
  const int* dst = ei + E;

  char* ws = (char*)d_ws;
  size_t o = 0;
  float* h    = (float*)(ws + o); o += (size_t)N*DH*sizeof(float);
  float* x0   = (float*)(ws + o); o += (size_t)N*DL*sizeof(float);
  float* bA   = (float*)(ws + o); o += (size_t)N*DL*sizeof(float);
  float* bB   = (float*)(ws + o); o += (size_t)N*DL*sizeof(float);
  int*   deg  = (int*)  (ws + o); o += (size_t)N*sizeof(int);
  int*   cur  = (int*)  (ws + o); o += (size_t)N*sizeof(int);
  float* dinv = (float*)(ws + o); o += (size_t)N*sizeof(float);
  int*   offs = (int*)  (ws + o); o += (size_t)(N+2)*sizeof(int);
  int*   part = (int*)  (ws + o); o += 4096;
  int*   csr  = (int*)  (ws + o); o += (size_t)E*sizeof(int);

  const int TB = 256;
  int gN  = (N + TB - 1) / TB;
  int gE  = (E + TB - 1) / TB;
  int nb  = (N + 1023) / 1024;

  // CSR build
  hipMemsetAsync(deg, 0, (size_t)N*sizeof(int), stream);
  k_count<<<gE, TB, 0, stream>>>(dst, deg, E);
  k_dinv<<<gN, TB, 0, stream>>>(deg, dinv, N);
  k_scan_part<<<nb, TB, 0, stream>>>(deg, part, N);
  k_scan_top<<<1, 1, 0, stream>>>(part, nb);
  k_scan_final<<<nb, TB, 0, stream>>>(deg, part, offs, N, E);
  hipMemsetAsync(cur, 0, (size_t)N*sizeof(int), stream);
  k_scatter<<<gE, TB, 0, stream>>>(src, dst, offs, cur, csr, E);
  k_sort<<<gN, TB, 0, stream>>>(csr, offs, N);

  // Encoder + flows
  k_gemm1<<<(N + BM - 1) / BM, TB, 0, stream>>>(x, W1, b1, h, N);
  k_flow<<<gN, TB, 0, stream>>>(h, W2, b2, pc, z0, ap, fb, x0, N);

  // APPNP: b starts at x0; 10 iterations ping-pong
  int gP = ((N*DL) + TB - 1) / TB;
  const float* bin = x0;
  for (int it = 0; it < KPROP; ++it){
    float* bout = (it % 2 == 0) ? bA : bB;
    k_prop<<<gP, TB, 0, stream>>>(bin, x0, bout, csr, offs, dinv, N);
    bin = bout;
  }

  // Final (after 10 iters, result is in bB)
  k_final<<<gN, TB, 0, stream>>>(bB, out, N);
}

// Round 2
// 1172.649 us; speedup vs baseline: 1.4663x; 1.4663x over previous
//
#include <hip/hip_runtime.h>
#include <math.h>
#include <limits.h>

#define DF 512
#define DH 64
#define DL 16
#define NC 10
#define NF 10
#define KPROP 10

__device__ __forceinline__ float softplus_(float x){
  return fmaxf(x, 0.0f) + log1pf(expf(-fabsf(x)));
}

// ---------------- GEMM1: h = relu(x @ W1 + b1) ----------------
#define BM 64
#define BN 64
#define BK 32
__global__ __launch_bounds__(256) void k_gemm1(const float* __restrict__ x,
    const float* __restrict__ W1, const float* __restrict__ b1,
    float* __restrict__ h, int N)
{
  __shared__ float At[BK][BM+4];   // A transposed: At[k][m]
  __shared__ float Bs[BK][BN+4];
  const int tid = threadIdx.x;
  const int tx = tid & 15, ty = tid >> 4;   // 16x16 thread grid, 4x4 microtile
  const int row0 = blockIdx.x * BM;
  float acc[4][4] = {};
  for (int k0 = 0; k0 < DF; k0 += BK) {
    #pragma unroll
    for (int i = 0; i < 2; ++i) {
      int idx = tid + i*256;            // 0..511 float4 slots
      int r  = idx >> 3;                // 8 float4 per 32-wide row
      int kk = (idx & 7) << 2;
      int row = row0 + r;
      float4 va = make_float4(0.f,0.f,0.f,0.f);
      if (row < N) va = *(const float4*)&x[(size_t)row*DF + k0 + kk];
      At[kk+0][r]=va.x; At[kk+1][r]=va.y; At[kk+2][r]=va.z; At[kk+3][r]=va.w;
      int r2 = idx >> 4;                // 16 float4 per 64-wide row
      int c4 = (idx & 15) << 2;
      float4 vb = *(const float4*)&W1[(size_t)(k0+r2)*DH + c4];
      Bs[r2][c4+0]=vb.x; Bs[r2][c4+1]=vb.y; Bs[r2][c4+2]=vb.z; Bs[r2][c4+3]=vb.w;
    }
    __syncthreads();
    #pragma unroll
    for (int kk = 0; kk < BK; ++kk) {
      float4 av = *(const float4*)&At[kk][ty<<2];
      float4 bv = *(const float4*)&Bs[kk][tx<<2];
      float a4[4]={av.x,av.y,av.z,av.w};
      float b4[4]={bv.x,bv.y,bv.z,bv.w};
      #pragma unroll
      for (int i=0;i<4;++i)
        #pragma unroll
        for (int j=0;j<4;++j) acc[i][j] = fmaf(a4[i], b4[j], acc[i][j]);
    }
    __syncthreads();
  }
  #pragma unroll
  for (int i=0;i<4;++i){
    int row = row0 + (ty<<2) + i;
    if (row < N){
      #pragma unroll
      for (int j=0;j<4;++j){
        int col = (tx<<2)+j;
        float v = acc[i][j] + b1[col];
        h[(size_t)row*DH + col] = fmaxf(v, 0.0f);
      }
    }
  }
}

// ------------- z = h@W2 + b2 ; radial flows ; beta_ft -------------
__global__ __launch_bounds__(256) void k_flow(const float* __restrict__ h,
    const float* __restrict__ W2, const float* __restrict__ b2,
    const float* __restrict__ pc, const float* __restrict__ z0g,
    const float* __restrict__ apg, const float* __restrict__ fbg,
    float* __restrict__ x0, int N)
{
  __shared__ float W2s[DH][DL+1];
  __shared__ float z0s[NF][NC][DL];
  __shared__ float alps[NF][NC];
  __shared__ float bhs[NF][NC];
  __shared__ float lpc[NC];
  __shared__ float b2s[DL];
  int tid = threadIdx.x;
  for (int i = tid; i < DH*DL; i += 256) W2s[i>>4][i&15] = W2[i];
  for (int i = tid; i < NF*NC*DL; i += 256) z0s[(i>>4)/NC][(i>>4)%NC][i&15] = z0g[i];
  if (tid < NF*NC){
    int l = tid/NC, c = tid%NC;
    float al = softplus_(apg[tid]);
    alps[l][c] = al;
    bhs[l][c]  = -al + softplus_(fbg[tid]);
  }
  if (tid < NC) lpc[tid] = logf(pc[tid]);
  if (tid < DL) b2s[tid] = b2[tid];
  __syncthreads();
  int n = blockIdx.x*256 + tid;
  if (n >= N) return;

  float z[DL];
  #pragma unroll
  for (int d=0; d<DL; ++d) z[d] = b2s[d];
  const float* hp = h + (size_t)n*DH;
  for (int k=0; k<DH; k+=4){
    float4 hv = *(const float4*)&hp[k];
    float hvv[4] = {hv.x,hv.y,hv.z,hv.w};
    #pragma unroll
    for (int kk=0; kk<4; ++kk)
      #pragma unroll
      for (int d=0; d<DL; ++d) z[d] = fmaf(hvv[kk], W2s[k+kk][d], z[d]);
  }

  const float NEGHALFD_LOG2PI = -14.703016531274762f;  // -8*log(2*pi)
  const float LOGSCALE        =  20.248193975754326f;  //  8*log(4*pi)
  #pragma unroll 1
  for (int c=0; c<NC; ++c){
    float zz[DL];
    #pragma unroll
    for (int d=0; d<DL; ++d) zz[d] = z[d];
    float sld = 0.f;
    #pragma unroll 1
    for (int l=0; l<NF; ++l){
      float al = alps[l][c], bhat = bhs[l][c];
      float dz[DL]; float r2 = 0.f;
      #pragma unroll
      for (int d=0; d<DL; ++d){ float t = zz[d] - z0s[l][c][d]; dz[d]=t; r2 = fmaf(t,t,r2); }
      float r  = sqrtf(r2);
      float hh = 1.0f/(al + r);
      float bh = bhat*hh;
      #pragma unroll
      for (int d=0; d<DL; ++d) zz[d] = fmaf(bh, dz[d], zz[d]);
      sld += 15.0f*log1pf(bh) + log1pf(bh - bhat*r*hh*hh);
    }
    float q2 = 0.f;
    #pragma unroll
    for (int d=0; d<DL; ++d) q2 = fmaf(zz[d], zz[d], q2);
    float v = -0.5f*q2 + NEGHALFD_LOG2PI + sld + lpc[c] + LOGSCALE;
    v = fminf(fmaxf(v, -30.f), 30.f);
    x0[(size_t)n*DL + c] = expf(v);
  }
  #pragma unroll
  for (int c=NC; c<DL; ++c) x0[(size_t)n*DL + c] = 0.f;
}

// ---------------- CSR construction ----------------
__global__ void k_count(const int* __restrict__ dst, int* __restrict__ deg, int E){
  int e = blockIdx.x*256 + threadIdx.x;
  if (e < E) atomicAdd(&deg[dst[e]], 1);
}

__global__ void k_dinv(const int* __restrict__ deg, float* __restrict__ dinv, int N){
  int n = blockIdx.x*256 + threadIdx.x;
  if (n < N) dinv[n] = 1.0f / sqrtf((float)(deg[n] + 1));   // +1 self loop
}

__global__ __launch_bounds__(256) void k_scan_part(const int* __restrict__ deg,
    int* __restrict__ part, int N){
  __shared__ int sd[256];
  int base = blockIdx.x*1024;
  int tid = threadIdx.x;
  int s = 0;
  #pragma unroll
  for (int i=0;i<4;++i){ int idx = base + tid*4 + i; if (idx < N) s += deg[idx]; }
  sd[tid] = s; __syncthreads();
  for (int ofs=128; ofs>0; ofs>>=1){ if (tid<ofs) sd[tid]+=sd[tid+ofs]; __syncthreads(); }
  if (tid==0) part[blockIdx.x] = sd[0];
}

__global__ void k_scan_top(int* part, int nb){
  if (blockIdx.x==0 && threadIdx.x==0){
    int run = 0;
    for (int i=0;i<nb;++i){ int v = part[i]; part[i] = run; run += v; }
  }
}

__global__ __launch_bounds__(256) void k_scan_final(const int* __restrict__ deg,
    const int* __restrict__ part, int* __restrict__ off, int N, int E)
{
  __shared__ int sc[256];
  int base = blockIdx.x*1024;
  int tid = threadIdx.x;
  int v[4]; int s = 0;
  #pragma unroll
  for (int i=0;i<4;++i){ int idx = base + tid*4 + i; v[i] = (idx<N)?deg[idx]:0; s += v[i]; }
  sc[tid] = s; __syncthreads();
  for (int ofs=1; ofs<256; ofs<<=1){
    int t = (tid>=ofs) ? sc[tid-ofs] : 0;
    __syncthreads();
    sc[tid] += t;
    __syncthreads();
  }
  int ex = sc[tid] - s + part[blockIdx.x];
  #pragma unroll
  for (int i=0;i<4;++i){
    int idx = base + tid*4 + i;
    if (idx < N){
      off[idx] = ex;
      if (idx == N-1) off[N] = ex + v[i];
      ex += v[i];
    }
  }
}

__global__ void k_scatter(const int* __restrict__ src, const int* __restrict__ dst,
    const int* __restrict__ off, int* __restrict__ cur, int* __restrict__ csr, int E){
  int e = blockIdx.x*256 + threadIdx.x;
  if (e < E){
    int d = dst[e];
    int p = off[d] + atomicAdd(&cur[d], 1);
    csr[p] = src[e];
  }
}

// ---- canonicalize segment order (stable value-rank via shuffles) ----
// One wave per node. Also emits per-edge weight w[i] = dinv[src]*dinv[dst]
// aligned with the canonical csr order.
__global__ __launch_bounds__(256) void k_rank(int* __restrict__ csr,
    float* __restrict__ w, const int* __restrict__ off,
    const float* __restrict__ dinv, int N)
{
  int wid  = (blockIdx.x*256 + threadIdx.x) >> 6;   // global wave id = node
  int lane = threadIdx.x & 63;
  if (wid >= N) return;
  int s = off[wid], e = off[wid+1];
  int d = e - s;
  if (d <= 0) return;
  float dn = dinv[wid];
  if (d == 1){
    if (lane == 0) w[s] = dinv[csr[s]] * dn;
    return;
  }
  if (d <= 64){
    int v = (lane < d) ? csr[s+lane] : INT_MAX;
    int rank = 0;
    for (int j = 0; j < d; ++j){
      int bv = __shfl(v, j);
      rank += (bv < v) || (bv == v && j < lane);
    }
    if (lane < d){ csr[s+rank] = v; w[s+rank] = dinv[v]*dn; }
  } else if (d <= 256){
    int v0 = (lane      < d) ? csr[s+lane      ] : INT_MAX;
    int v1 = (lane+64   < d) ? csr[s+lane+64   ] : INT_MAX;
    int v2 = (lane+128  < d) ? csr[s+lane+128  ] : INT_MAX;
    int v3 = (lane+192  < d) ? csr[s+lane+192  ] : INT_MAX;
    int r0=0,r1=0,r2=0,r3=0;
    for (int j = 0; j < d; ++j){
      int slot = j >> 6, jl = j & 63;
      int bv = (slot==0) ? __shfl(v0,jl) : (slot==1) ? __shfl(v1,jl)
             : (slot==2) ? __shfl(v2,jl) : __shfl(v3,jl);
      r0 += (bv < v0) || (bv == v0 && j < lane);
      r1 += (bv < v1) || (bv == v1 && j < lane+64);
      r2 += (bv < v2) || (bv == v2 && j < lane+128);
      r3 += (bv < v3) || (bv == v3 && j < lane+192);
    }
    if (lane      < d){ csr[s+r0]=v0; w[s+r0]=dinv[v0]*dn; }
    if (lane+64   < d){ csr[s+r1]=v1; w[s+r1]=dinv[v1]*dn; }
    if (lane+128  < d){ csr[s+r2]=v2; w[s+r2]=dinv[v2]*dn; }
    if (lane+192  < d){ csr[s+r3]=v3; w[s+r3]=dinv[v3]*dn; }
  } else {
    // practically impossible for this degree distribution; serial fallback
    if (lane == 0){
      for (int i = s+1; i < e; ++i){
        int key = csr[i]; int j = i-1;
        while (j >= s && csr[j] > key){ csr[j+1] = csr[j]; --j; }
        csr[j+1] = key;
      }
      for (int i = s; i < e; ++i) w[i] = dinv[csr[i]]*dn;
    }
  }
}

// ---------------- APPNP iteration ----------------
__global__ __launch_bounds__(256) void k_prop(const float* __restrict__ bsrc,
    const float* __restrict__ x0, float* __restrict__ bdst,
    const int* __restrict__ csr, const int* __restrict__ off,
    const float* __restrict__ w, const float* __restrict__ dinv, int N)
{
  int t = blockIdx.x*256 + threadIdx.x;
  int n = t >> 4, lane = t & 15;
  if (n >= N) return;
  float dn = dinv[n];
  int s = off[n], e = off[n+1];
  float acc0 = dn*dn*bsrc[(size_t)n*DL + lane];    // self loop
  float acc1 = 0.f;
  int i = s;
  for (; i+2 <= e; i += 2){
    int  s0 = csr[i],  s1 = csr[i+1];
    float w0 = w[i],   w1 = w[i+1];
    acc0 = fmaf(w0, bsrc[(size_t)s0*DL + lane], acc0);
    acc1 = fmaf(w1, bsrc[(size_t)s1*DL + lane], acc1);
  }
  if (i < e) acc0 = fmaf(w[i], bsrc[(size_t)csr[i]*DL + lane], acc0);
  float out = fmaf(0.9f, acc0+acc1, 0.1f*x0[(size_t)n*DL + lane]);
  bdst[(size_t)n*DL + lane] = out;
}

// ---- last APPNP iteration fused with alpha/soft/argmax ----
__global__ __launch_bounds__(256) void k_prop_final(const float* __restrict__ bsrc,
    const float* __restrict__ x0,
    const int* __restrict__ csr, const int* __restrict__ off,
    const float* __restrict__ w, const float* __restrict__ dinv,
    float* __restrict__ out, int N)
{
  int t = blockIdx.x*256 + threadIdx.x;
  int n = t >> 4, lane = t & 15;
  if (n >= N) return;
  float dn = dinv[n];
  int s = off[n], e = off[n+1];
  float acc0 = dn*dn*bsrc[(size_t)n*DL + lane];
  float acc1 = 0.f;
  int i = s;
  for (; i+2 <= e; i += 2){
    int  s0 = csr[i],  s1 = csr[i+1];
    float w0 = w[i],   w1 = w[i+1];
    acc0 = fmaf(w0, bsrc[(size_t)s0*DL + lane], acc0);
    acc1 = fmaf(w1, bsrc[(size_t)s1*DL + lane], acc1);
  }
  if (i < e) acc0 = fmaf(w[i], bsrc[(size_t)csr[i]*DL + lane], acc0);
  float beta  = fmaf(0.9f, acc0+acc1, 0.1f*x0[(size_t)n*DL + lane]);
  float alpha = 1.0f + beta;

  // sum over the 10 real classes (16-lane group reduction)
  float sv = (lane < NC) ? alpha : 0.f;
  #pragma unroll
  for (int o = 8; o; o >>= 1) sv += __shfl_xor(sv, o, 16);
  // soft per lane, then argmax on soft with first-index tie-break
  float soft = alpha / sv;
  float v  = (lane < NC) ? soft : -1e30f;
  int  idx = (lane < NC) ? lane : 999;
  #pragma unroll
  for (int o = 8; o; o >>= 1){
    float vo = __shfl_xor(v, o, 16);
    int  io  = __shfl_xor(idx, o, 16);
    if (vo > v || (vo == v && io < idx)){ v = vo; idx = io; }
  }
  if (lane < NC) out[(size_t)N + (size_t)n*NC + lane] = soft;
  if (lane == 0) out[n] = (float)idx;
}

extern "C" void kernel_launch(void* const* d_in, const int* in_sizes, int n_in,
                              void* d_out, int out_size, void* d_ws, size_t ws_size,
                              hipStream_t stream)
{
  const float* x  = (const float*)d_in[0];
  const int*   ei = (const int*)  d_in[1];
  const float* pc = (const float*)d_in[2];
  const float* W1 = (const float*)d_in[3];
  const float* b1 = (const float*)d_in[4];
  const float* W2 = (const float*)d_in[5];
  const float* b2 = (const float*)d_in[6];
  const float* z0 = (const float*)d_in[7];
  const float* ap = (const float*)d_in[8];
  const float* fb = (const float*)d_in[9];
  float* out = (float*)d_out;

  const int N = in_sizes[0] / DF;
  const int E = in_sizes[1] / 2;
  const int* src = ei;
  const int* dst = ei + E;

  // Workspace layout. region0 (size max(N*DH, 2*E) floats) is used first for
  // h (encoder output), then — after k_flow has consumed h — reused for
  // csr[E] + w[E].
  char* ws = (char*)d_ws;
  size_t o = 0;
  size_t region0 = (size_t)N*DH*sizeof(float);
  size_t csrw    = (size_t)E*2*sizeof(float);
  if (csrw > region0) region0 = csrw;
  float* h    = (float*)(ws + o);
  int*   csr  = (int*)  (ws + o);
  float* w    = (float*)(ws + o + (size_t)E*sizeof(int));
  o += region0;
  float* x0   = (float*)(ws + o); o += (size_t)N*DL*sizeof(float);
  float* bA   = (float*)(ws + o); o += (size_t)N*DL*sizeof(float);
  float* bB   = (float*)(ws + o); o += (size_t)N*DL*sizeof(float);
  int*   deg  = (int*)  (ws + o); o += (size_t)N*sizeof(int);
  int*   cur  = (int*)  (ws + o); o += (size_t)N*sizeof(int);
  float* dinv = (float*)(ws + o); o += (size_t)N*sizeof(float);
  int*   offs = (int*)  (ws + o); o += (size_t)(N+2)*sizeof(int);
  int*   part = (int*)  (ws + o); o += 4096;

  const int TB = 256;
  int gN  = (N + TB - 1) / TB;
  int gE  = (E + TB - 1) / TB;
  int nb  = (N + 1023) / 1024;

  // Phase 1: encoder + flows (uses h region)
  k_gemm1<<<(N + BM - 1) / BM, TB, 0, stream>>>(x, W1, b1, h, N);
  k_flow<<<gN, TB, 0, stream>>>(h, W2, b2, pc, z0, ap, fb, x0, N);

  // Phase 2: CSR build (reuses h region for csr + w)
  hipMemsetAsync(deg, 0, (size_t)N*sizeof(int), stream);
  k_count<<<gE, TB, 0, stream>>>(dst, deg, E);
  k_dinv<<<gN, TB, 0, stream>>>(deg, dinv, N);
  k_scan_part<<<nb, TB, 0, stream>>>(deg, part, N);
  k_scan_top<<<1, 1, 0, stream>>>(part, nb);
  k_scan_final<<<nb, TB, 0, stream>>>(deg, part, offs, N, E);
  hipMemsetAsync(cur, 0, (size_t)N*sizeof(int), stream);
  k_scatter<<<gE, TB, 0, stream>>>(src, dst, offs, cur, csr, E);
  k_rank<<<(N + 3) / 4, TB, 0, stream>>>(csr, w, offs, dinv, N);

  // Phase 3: APPNP — 9 plain iterations + 1 fused with the epilogue
  int gP = ((N*DL) + TB - 1) / TB;
  const float* bin = x0;
  for (int it = 0; it < KPROP-1; ++it){
    float* bout = (it & 1) ? bB : bA;
    k_prop<<<gP, TB, 0, stream>>>(bin, x0, bout, csr, offs, w, dinv, N);
    bin = bout;
  }
  k_prop_final<<<gP, TB, 0, stream>>>(bin, x0, csr, offs, w, dinv, out, N);
}

// Round 3
// 873.786 us; speedup vs baseline: 1.9678x; 1.3420x over previous
//
#include <hip/hip_runtime.h>
#include <math.h>
#include <limits.h>

#define DF 512
#define DH 64
#define DL 16
#define NC 10
#define NF 10
#define KPROP 10

#define BSH 7                  // bucket shift: 128 nodes per bucket
#define BW  (1 << BSH)
#define MAXB 1024              // max buckets (N <= 131072)
#define TILE 16384             // edges per block in bucket scatter

__device__ __forceinline__ float softplus_(float x){
  return fmaxf(x, 0.0f) + log1pf(expf(-fabsf(x)));
}

// ---------------- GEMM1: h = relu(x @ W1 + b1) ----------------
#define BM 64
#define BN 64
#define BK 32
__global__ __launch_bounds__(256) void k_gemm1(const float* __restrict__ x,
    const float* __restrict__ W1, const float* __restrict__ b1,
    float* __restrict__ h, int N)
{
  __shared__ float At[BK][BM+4];
  __shared__ float Bs[BK][BN+4];
  const int tid = threadIdx.x;
  const int tx = tid & 15, ty = tid >> 4;
  const int row0 = blockIdx.x * BM;
  float acc[4][4] = {};
  for (int k0 = 0; k0 < DF; k0 += BK) {
    #pragma unroll
    for (int i = 0; i < 2; ++i) {
      int idx = tid + i*256;
      int r  = idx >> 3;
      int kk = (idx & 7) << 2;
      int row = row0 + r;
      float4 va = make_float4(0.f,0.f,0.f,0.f);
      if (row < N) va = *(const float4*)&x[(size_t)row*DF + k0 + kk];
      At[kk+0][r]=va.x; At[kk+1][r]=va.y; At[kk+2][r]=va.z; At[kk+3][r]=va.w;
      int r2 = idx >> 4;
      int c4 = (idx & 15) << 2;
      float4 vb = *(const float4*)&W1[(size_t)(k0+r2)*DH + c4];
      Bs[r2][c4+0]=vb.x; Bs[r2][c4+1]=vb.y; Bs[r2][c4+2]=vb.z; Bs[r2][c4+3]=vb.w;
    }
    __syncthreads();
    #pragma unroll
    for (int kk = 0; kk < BK; ++kk) {
      float4 av = *(const float4*)&At[kk][ty<<2];
      float4 bv = *(const float4*)&Bs[kk][tx<<2];
      float a4[4]={av.x,av.y,av.z,av.w};
      float b4[4]={bv.x,bv.y,bv.z,bv.w};
      #pragma unroll
      for (int i=0;i<4;++i)
        #pragma unroll
        for (int j=0;j<4;++j) acc[i][j] = fmaf(a4[i], b4[j], acc[i][j]);
    }
    __syncthreads();
  }
  #pragma unroll
  for (int i=0;i<4;++i){
    int row = row0 + (ty<<2) + i;
    if (row < N){
      #pragma unroll
      for (int j=0;j<4;++j){
        int col = (tx<<2)+j;
        float v = acc[i][j] + b1[col];
        h[(size_t)row*DH + col] = fmaxf(v, 0.0f);
      }
    }
  }
}

// ------------- z = h@W2 + b2 ; radial flows ; beta_ft -------------
__global__ __launch_bounds__(256) void k_flow(const float* __restrict__ h,
    const float* __restrict__ W2, const float* __restrict__ b2,
    const float* __restrict__ pc, const float* __restrict__ z0g,
    const float* __restrict__ apg, const float* __restrict__ fbg,
    float* __restrict__ x0, int N)
{
  __shared__ float W2s[DH][DL+1];
  __shared__ float z0s[NF][NC][DL];
  __shared__ float alps[NF][NC];
  __shared__ float bhs[NF][NC];
  __shared__ float lpc[NC];
  __shared__ float b2s[DL];
  int tid = threadIdx.x;
  for (int i = tid; i < DH*DL; i += 256) W2s[i>>4][i&15] = W2[i];
  for (int i = tid; i < NF*NC*DL; i += 256) z0s[(i>>4)/NC][(i>>4)%NC][i&15] = z0g[i];
  if (tid < NF*NC){
    int l = tid/NC, c = tid%NC;
    float al = softplus_(apg[tid]);
    alps[l][c] = al;
    bhs[l][c]  = -al + softplus_(fbg[tid]);
  }
  if (tid < NC) lpc[tid] = logf(pc[tid]);
  if (tid < DL) b2s[tid] = b2[tid];
  __syncthreads();
  int n = blockIdx.x*256 + tid;
  if (n >= N) return;

  float z[DL];
  #pragma unroll
  for (int d=0; d<DL; ++d) z[d] = b2s[d];
  const float* hp = h + (size_t)n*DH;
  for (int k=0; k<DH; k+=4){
    float4 hv = *(const float4*)&hp[k];
    float hvv[4] = {hv.x,hv.y,hv.z,hv.w};
    #pragma unroll
    for (int kk=0; kk<4; ++kk)
      #pragma unroll
      for (int d=0; d<DL; ++d) z[d] = fmaf(hvv[kk], W2s[k+kk][d], z[d]);
  }

  const float NEGHALFD_LOG2PI = -14.703016531274762f;
  const float LOGSCALE        =  20.248193975754326f;
  #pragma unroll 1
  for (int c=0; c<NC; ++c){
    float zz[DL];
    #pragma unroll
    for (int d=0; d<DL; ++d) zz[d] = z[d];
    float sld = 0.f;
    #pragma unroll 1
    for (int l=0; l<NF; ++l){
      float al = alps[l][c], bhat = bhs[l][c];
      float dz[DL]; float r2 = 0.f;
      #pragma unroll
      for (int d=0; d<DL; ++d){ float t = zz[d] - z0s[l][c][d]; dz[d]=t; r2 = fmaf(t,t,r2); }
      float r  = sqrtf(r2);
      float hh = 1.0f/(al + r);
      float bh = bhat*hh;
      #pragma unroll
      for (int d=0; d<DL; ++d) zz[d] = fmaf(bh, dz[d], zz[d]);
      sld += 15.0f*log1pf(bh) + log1pf(bh - bhat*r*hh*hh);
    }
    float q2 = 0.f;
    #pragma unroll
    for (int d=0; d<DL; ++d) q2 = fmaf(zz[d], zz[d], q2);
    float v = -0.5f*q2 + NEGHALFD_LOG2PI + sld + lpc[c] + LOGSCALE;
    v = fminf(fmaxf(v, -30.f), 30.f);
    x0[(size_t)n*DL + c] = expf(v);
  }
  #pragma unroll
  for (int c=NC; c<DL; ++c) x0[(size_t)n*DL + c] = 0.f;
}

// ---------------- bucketed CSR construction ----------------
// Pass A1: bucket histogram
__global__ __launch_bounds__(256) void k_bhist(const int* __restrict__ dst,
    int* __restrict__ bCnt, int E, int B)
{
  __shared__ int hh[MAXB];
  int tid = threadIdx.x;
  for (int b = tid; b < B; b += 256) hh[b] = 0;
  __syncthreads();
  for (int i = blockIdx.x*256 + tid; i < E; i += gridDim.x*256)
    atomicAdd(&hh[dst[i] >> BSH], 1);
  __syncthreads();
  for (int b = tid; b < B; b += 256) if (hh[b]) atomicAdd(&bCnt[b], hh[b]);
}

// Pass A2: tiny serial scan over buckets
__global__ void k_bscan(const int* __restrict__ bCnt, int* __restrict__ bOff, int B){
  if (blockIdx.x==0 && threadIdx.x==0){
    int run = 0;
    for (int b=0;b<B;++b){ bOff[b]=run; run+=bCnt[b]; }
    bOff[B]=run;
  }
}

// Pass A3: scatter packed (src<<BSH | dst_local) into bucket regions,
// per-block chunk reservation for write locality.
__global__ __launch_bounds__(256) void k_bscatter(const int* __restrict__ src,
    const int* __restrict__ dst, const int* __restrict__ bOff,
    int* __restrict__ bCur, int* __restrict__ bp, int E, int B)
{
  __shared__ int hc[MAXB];
  __shared__ int hb[MAXB];
  int tid = threadIdx.x;
  int base = blockIdx.x * TILE;
  int lim  = base + TILE; if (lim > E) lim = E;
  for (int b = tid; b < B; b += 256) hc[b] = 0;
  __syncthreads();
  for (int i = base + tid; i < lim; i += 256)
    atomicAdd(&hc[dst[i] >> BSH], 1);
  __syncthreads();
  for (int b = tid; b < B; b += 256){
    int c = hc[b];
    hb[b] = c ? atomicAdd(&bCur[b], c) : 0;
    hc[b] = 0;
  }
  __syncthreads();
  for (int i = base + tid; i < lim; i += 256){
    int d = dst[i];
    int b = d >> BSH;
    int pos = bOff[b] + hb[b] + atomicAdd(&hc[b], 1);
    bp[pos] = (src[i] << BSH) | (d & (BW-1));
  }
}

// Pass B1: per-bucket degree count (LDS counters, coalesced writes)
__global__ __launch_bounds__(256) void k_bdeg(const int* __restrict__ bp,
    const int* __restrict__ bOff, int* __restrict__ deg, int N)
{
  __shared__ int cur[BW];
  int tid = threadIdx.x;
  int b = blockIdx.x;
  if (tid < BW) cur[tid] = 0;
  __syncthreads();
  int s = bOff[b], e = bOff[b+1];
  for (int i = s + tid; i < e; i += 256)
    atomicAdd(&cur[bp[i] & (BW-1)], 1);
  __syncthreads();
  int node = (b << BSH) + tid;
  if (tid < BW && node < N) deg[node] = cur[tid];
}

__global__ void k_dinv(const int* __restrict__ deg, float* __restrict__ dinv, int N){
  int n = blockIdx.x*256 + threadIdx.x;
  if (n < N) dinv[n] = 1.0f / sqrtf((float)(deg[n] + 1));
}

// -------- scan of deg -> off (3 kernels, as before) --------
__global__ __launch_bounds__(256) void k_scan_part(const int* __restrict__ deg,
    int* __restrict__ part, int N){
  __shared__ int sd[256];
  int base = blockIdx.x*1024;
  int tid = threadIdx.x;
  int s = 0;
  #pragma unroll
  for (int i=0;i<4;++i){ int idx = base + tid*4 + i; if (idx < N) s += deg[idx]; }
  sd[tid] = s; __syncthreads();
  for (int ofs=128; ofs>0; ofs>>=1){ if (tid<ofs) sd[tid]+=sd[tid+ofs]; __syncthreads(); }
  if (tid==0) part[blockIdx.x] = sd[0];
}

__global__ void k_scan_top(int* part, int nb){
  if (blockIdx.x==0 && threadIdx.x==0){
    int run = 0;
    for (int i=0;i<nb;++i){ int v = part[i]; part[i] = run; run += v; }
  }
}

__global__ __launch_bounds__(256) void k_scan_final(const int* __restrict__ deg,
    const int* __restrict__ part, int* __restrict__ off, int N, int E)
{
  __shared__ int sc[256];
  int base = blockIdx.x*1024;
  int tid = threadIdx.x;
  int v[4]; int s = 0;
  #pragma unroll
  for (int i=0;i<4;++i){ int idx = base + tid*4 + i; v[i] = (idx<N)?deg[idx]:0; s += v[i]; }
  sc[tid] = s; __syncthreads();
  for (int ofs=1; ofs<256; ofs<<=1){
    int t = (tid>=ofs) ? sc[tid-ofs] : 0;
    __syncthreads();
    sc[tid] += t;
    __syncthreads();
  }
  int ex = sc[tid] - s + part[blockIdx.x];
  #pragma unroll
  for (int i=0;i<4;++i){
    int idx = base + tid*4 + i;
    if (idx < N){
      off[idx] = ex;
      if (idx == N-1) off[N] = ex + v[i];
      ex += v[i];
    }
  }
}

// Pass B2: place (src, w) pairs at CSR positions (writes stay in-bucket -> L2)
__global__ __launch_bounds__(256) void k_place(const int* __restrict__ bp,
    const int* __restrict__ bOff, const int* __restrict__ off,
    const float* __restrict__ dinv, float2* __restrict__ csrw, int N)
{
  __shared__ int cur[BW];
  int tid = threadIdx.x;
  int b = blockIdx.x;
  if (tid < BW) cur[tid] = 0;
  __syncthreads();
  int node0 = b << BSH;
  int s = bOff[b], e = bOff[b+1];
  for (int i = s + tid; i < e; i += 256){
    int v  = bp[i];
    int dl = v & (BW-1);
    int sn = v >> BSH;
    int d  = node0 + dl;
    int p  = off[d] + atomicAdd(&cur[dl], 1);
    csrw[p] = make_float2(__int_as_float(sn), dinv[sn]*dinv[d]);
  }
}

// ---- canonicalize segment order (stable value-rank via shuffles) ----
__global__ __launch_bounds__(256) void k_rank(float2* __restrict__ csrw,
    const int* __restrict__ off, int N)
{
  int wid  = (blockIdx.x*256 + threadIdx.x) >> 6;
  int lane = threadIdx.x & 63;
  if (wid >= N) return;
  int s = off[wid], e = off[wid+1];
  int d = e - s;
  if (d <= 1) return;
  if (d <= 64){
    float2 pv = (lane < d) ? csrw[s+lane] : make_float2(__int_as_float(INT_MAX), 0.f);
    int v = __float_as_int(pv.x);
    int rank = 0;
    for (int j = 0; j < d; ++j){
      int bv = __shfl(v, j);
      rank += (bv < v) || (bv == v && j < lane);
    }
    if (lane < d) csrw[s+rank] = pv;
  } else if (d <= 256){
    float2 p0 = (lane      < d) ? csrw[s+lane      ] : make_float2(__int_as_float(INT_MAX),0.f);
    float2 p1 = (lane+64   < d) ? csrw[s+lane+64   ] : make_float2(__int_as_float(INT_MAX),0.f);
    float2 p2 = (lane+128  < d) ? csrw[s+lane+128  ] : make_float2(__int_as_float(INT_MAX),0.f);
    float2 p3 = (lane+192  < d) ? csrw[s+lane+192  ] : make_float2(__int_as_float(INT_MAX),0.f);
    int v0=__float_as_int(p0.x), v1=__float_as_int(p1.x);
    int v2=__float_as_int(p2.x), v3=__float_as_int(p3.x);
    int r0=0,r1=0,r2=0,r3=0;
    for (int j = 0; j < d; ++j){
      int slot = j >> 6, jl = j & 63;
      int bv = (slot==0) ? __shfl(v0,jl) : (slot==1) ? __shfl(v1,jl)
             : (slot==2) ? __shfl(v2,jl) : __shfl(v3,jl);
      r0 += (bv < v0) || (bv == v0 && j < lane);
      r1 += (bv < v1) || (bv == v1 && j < lane+64);
      r2 += (bv < v2) || (bv == v2 && j < lane+128);
      r3 += (bv < v3) || (bv == v3 && j < lane+192);
    }
    if (lane      < d) csrw[s+r0]=p0;
    if (lane+64   < d) csrw[s+r1]=p1;
    if (lane+128  < d) csrw[s+r2]=p2;
    if (lane+192  < d) csrw[s+r3]=p3;
  } else {
    if (lane == 0){
      for (int i = s+1; i < e; ++i){
        float2 key = csrw[i];
        int kv = __float_as_int(key.x);
        int j = i-1;
        while (j >= s && __float_as_int(csrw[j].x) > kv){ csrw[j+1] = csrw[j]; --j; }
        csrw[j+1] = key;
      }
    }
  }
}

// ---------------- APPNP iteration: 4 threads/node, float4 ----------------
__global__ __launch_bounds__(256) void k_prop(const float* __restrict__ bsrc,
    const float* __restrict__ x0, float* __restrict__ bdst,
    const float2* __restrict__ csrw, const int* __restrict__ off,
    const float* __restrict__ dinv, int N)
{
  int t = blockIdx.x*256 + threadIdx.x;
  int n = t >> 2, q = t & 3;
  if (n >= N) return;
  const float4* b4 = (const float4*)bsrc;
  float dn = dinv[n];
  float4 self = b4[(size_t)n*4 + q];
  float wself = dn*dn;
  float4 a0, a1;
  a0.x = wself*self.x; a0.y = wself*self.y; a0.z = wself*self.z; a0.w = wself*self.w;
  a1.x = 0.f; a1.y = 0.f; a1.z = 0.f; a1.w = 0.f;
  int s = off[n], e = off[n+1];
  int i = s;
  for (; i+2 <= e; i += 2){
    float2 p0 = csrw[i], p1 = csrw[i+1];
    float4 v0 = b4[(size_t)__float_as_int(p0.x)*4 + q];
    float4 v1 = b4[(size_t)__float_as_int(p1.x)*4 + q];
    a0.x = fmaf(p0.y, v0.x, a0.x); a0.y = fmaf(p0.y, v0.y, a0.y);
    a0.z = fmaf(p0.y, v0.z, a0.z); a0.w = fmaf(p0.y, v0.w, a0.w);
    a1.x = fmaf(p1.y, v1.x, a1.x); a1.y = fmaf(p1.y, v1.y, a1.y);
    a1.z = fmaf(p1.y, v1.z, a1.z); a1.w = fmaf(p1.y, v1.w, a1.w);
  }
  if (i < e){
    float2 p0 = csrw[i];
    float4 v0 = b4[(size_t)__float_as_int(p0.x)*4 + q];
    a0.x = fmaf(p0.y, v0.x, a0.x); a0.y = fmaf(p0.y, v0.y, a0.y);
    a0.z = fmaf(p0.y, v0.z, a0.z); a0.w = fmaf(p0.y, v0.w, a0.w);
  }
  float4 xv = ((const float4*)x0)[(size_t)n*4 + q];
  float4 o;
  o.x = fmaf(0.9f, a0.x+a1.x, 0.1f*xv.x);
  o.y = fmaf(0.9f, a0.y+a1.y, 0.1f*xv.y);
  o.z = fmaf(0.9f, a0.z+a1.z, 0.1f*xv.z);
  o.w = fmaf(0.9f, a0.w+a1.w, 0.1f*xv.w);
  ((float4*)bdst)[(size_t)n*4 + q] = o;
}

// ---- last APPNP iteration fused with alpha/soft/argmax ----
__global__ __launch_bounds__(256) void k_prop_final(const float* __restrict__ bsrc,
    const float* __restrict__ x0,
    const float2* __restrict__ csrw, const int* __restrict__ off,
    const float* __restrict__ dinv, float* __restrict__ out, int N)
{
  int t = blockIdx.x*256 + threadIdx.x;
  int n = t >> 2, q = t & 3;
  if (n >= N) return;
  const float4* b4 = (const float4*)bsrc;
  float dn = dinv[n];
  float4 self = b4[(size_t)n*4 + q];
  float wself = dn*dn;
  float4 a0, a1;
  a0.x = wself*self.x; a0.y = wself*self.y; a0.z = wself*self.z; a0.w = wself*self.w;
  a1.x = 0.f; a1.y = 0.f; a1.z = 0.f; a1.w = 0.f;
  int s = off[n], e = off[n+1];
  int i = s;
  for (; i+2 <= e; i += 2){
    float2 p0 = csrw[i], p1 = csrw[i+1];
    float4 v0 = b4[(size_t)__float_as_int(p0.x)*4 + q];
    float4 v1 = b4[(size_t)__float_as_int(p1.x)*4 + q];
    a0.x = fmaf(p0.y, v0.x, a0.x); a0.y = fmaf(p0.y, v0.y, a0.y);
    a0.z = fmaf(p0.y, v0.z, a0.z); a0.w = fmaf(p0.y, v0.w, a0.w);
    a1.x = fmaf(p1.y, v1.x, a1.x); a1.y = fmaf(p1.y, v1.y, a1.y);
    a1.z = fmaf(p1.y, v1.z, a1.z); a1.w = fmaf(p1.y, v1.w, a1.w);
  }
  if (i < e){
    float2 p0 = csrw[i];
    float4 v0 = b4[(size_t)__float_as_int(p0.x)*4 + q];
    a0.x = fmaf(p0.y, v0.x, a0.x); a0.y = fmaf(p0.y, v0.y, a0.y);
    a0.z = fmaf(p0.y, v0.z, a0.z); a0.w = fmaf(p0.y, v0.w, a0.w);
  }
  float4 xv = ((const float4*)x0)[(size_t)n*4 + q];
  float4 al;
  al.x = fmaf(0.9f, a0.x+a1.x, fmaf(0.1f, xv.x, 1.f));
  al.y = fmaf(0.9f, a0.y+a1.y, fmaf(0.1f, xv.y, 1.f));
  al.z = fmaf(0.9f, a0.z+a1.z, fmaf(0.1f, xv.z, 1.f));
  al.w = fmaf(0.9f, a0.w+a1.w, fmaf(0.1f, xv.w, 1.f));

  // masked sum over 10 real classes (thread q covers classes 4q..4q+3)
  float sv = 0.f;
  if (q < 2)       sv = al.x + al.y + al.z + al.w;
  else if (q == 2) sv = al.x + al.y;
  sv += __shfl_xor(sv, 1, 4);
  sv += __shfl_xor(sv, 2, 4);

  // local argmax on alpha (same order as soft), first-index tie-break
  float bv = -1e30f; int bi = 999;
  int cb = q*4;
  int nvalid = (q < 2) ? 4 : (q == 2 ? 2 : 0);
  float av[4] = {al.x, al.y, al.z, al.w};
  for (int j = 0; j < nvalid; ++j){
    if (av[j] > bv){ bv = av[j]; bi = cb + j; }
  }
  #pragma unroll
  for (int o = 1; o <= 2; o <<= 1){
    float vo = __shfl_xor(bv, o, 4);
    int  io  = __shfl_xor(bi, o, 4);
    if (vo > bv || (vo == bv && io < bi)){ bv = vo; bi = io; }
  }

  float inv = 1.0f / sv;
  size_t sb = (size_t)N + (size_t)n*NC;
  for (int j = 0; j < nvalid; ++j) out[sb + cb + j] = av[j] * inv;
  if (q == 0) out[n] = (float)bi;
}

extern "C" void kernel_launch(void* const* d_in, const int* in_sizes, int n_in,
                              void* d_out, int out_size, void* d_ws, size_t ws_size,
                              hipStream_t stream)
{
  const float* x  = (const float*)d_in[0];
  const int*   ei = (const int*)  d_in[1];
  const float* pc = (const float*)d_in[2];
  const float* W1 = (const float*)d_in[3];
  const float* b1 = (const float*)d_in[4];
  const float* W2 = (const float*)d_in[5];
  const float* b2 = (const float*)d_in[6];
  const float* z0 = (const float*)d_in[7];
  const float* ap = (const float*)d_in[8];
  const float* fb = (const float*)d_in[9];
  float* out = (float*)d_out;

  const int N = in_sizes[0] / DF;
  const int E = in_sizes[1] / 2;
  const int* src = ei;
  const int* dst = ei + E;
  const int B = (N + BW - 1) >> BSH;   // buckets

  // Workspace: region0 = h (25.6MB), reused for bucket-packed edges after k_flow.
  char* ws = (char*)d_ws;
  size_t o = 0;
  size_t region0 = (size_t)N*DH*sizeof(float);
  if ((size_t)E*sizeof(int) > region0) region0 = (size_t)E*sizeof(int);
  float* h    = (float*)(ws + o);
  int*   bp   = (int*)  (ws + o);           // packed (src<<BSH | dst_local)
  o += region0;
  float2* csrw = (float2*)(ws + o); o += (size_t)E*sizeof(float2);
  float* x0   = (float*)(ws + o); o += (size_t)N*DL*sizeof(float);
  float* bA   = (float*)(ws + o); o += (size_t)N*DL*sizeof(float);
  float* bB   = (float*)(ws + o); o += (size_t)N*DL*sizeof(float);
  int*   deg  = (int*)  (ws + o); o += (size_t)N*sizeof(int);
  float* dinv = (float*)(ws + o); o += (size_t)N*sizeof(float);
  int*   offs = (int*)  (ws + o); o += (size_t)(N+2)*sizeof(int);
  int*   part = (int*)  (ws + o); o += 4096;
  int*   bCnt = (int*)  (ws + o); o += MAXB*sizeof(int);
  int*   bOff = (int*)  (ws + o); o += (MAXB+1)*sizeof(int);
  int*   bCur = (int*)  (ws + o); o += MAXB*sizeof(int);

  const int TB = 256;
  int gN  = (N + TB - 1) / TB;
  int nb  = (N + 1023) / 1024;

  // Phase 1: encoder + flows (uses h region)
  k_gemm1<<<(N + BM - 1) / BM, TB, 0, stream>>>(x, W1, b1, h, N);
  k_flow<<<gN, TB, 0, stream>>>(h, W2, b2, pc, z0, ap, fb, x0, N);

  // Phase 2: bucketed CSR build (reuses h region for bp)
  hipMemsetAsync(bCnt, 0, MAXB*sizeof(int), stream);
  hipMemsetAsync(bCur, 0, MAXB*sizeof(int), stream);
  k_bhist<<<512, TB, 0, stream>>>(dst, bCnt, E, B);
  k_bscan<<<1, 1, 0, stream>>>(bCnt, bOff, B);
  k_bscatter<<<(E + TILE - 1)/TILE, TB, 0, stream>>>(src, dst, bOff, bCur, bp, E, B);
  k_bdeg<<<B, TB, 0, stream>>>(bp, bOff, deg, N);
  k_dinv<<<gN, TB, 0, stream>>>(deg, dinv, N);
  k_scan_part<<<nb, TB, 0, stream>>>(deg, part, N);
  k_scan_top<<<1, 1, 0, stream>>>(part, nb);
  k_scan_final<<<nb, TB, 0, stream>>>(deg, part, offs, N, E);
  k_place<<<B, TB, 0, stream>>>(bp, bOff, offs, dinv, csrw, N);
  k_rank<<<(N + 3) / 4, TB, 0, stream>>>(csrw, offs, N);

  // Phase 3: APPNP — 9 plain iterations + 1 fused with the epilogue
  int gP = ((N*4) + TB - 1) / TB;
  const float* bin = x0;
  for (int it = 0; it < KPROP-1; ++it){
    float* bout = (it & 1) ? bB : bA;
    k_prop<<<gP, TB, 0, stream>>>(bin, x0, bout, csrw, offs, dinv, N);
    bin = bout;
  }
  k_prop_final<<<gP, TB, 0, stream>>>(bin, x0, csrw, offs, dinv, out, N);
}

// Round 4
// 826.978 us; speedup vs baseline: 2.0792x; 1.0566x over previous
//
#include <hip/hip_runtime.h>
#include <math.h>
#include <limits.h>

#define DF 512
#define DH 64
#define DL 16
#define NC 10
#define NF 10
#define KPROP 10

#define BSH 7                  // bucket shift: 128 nodes per bucket
#define BW  (1 << BSH)
#define MAXB 1024
#define TILE 16384

__device__ __forceinline__ float softplus_(float x){
  return fmaxf(x, 0.0f) + log1pf(expf(-fabsf(x)));
}

// -------- GEMM1 fused with z-projection: z = relu(x@W1+b1) @ W2 + b2 --------
#define BM 64
#define BN 64
#define BK 32
__global__ __launch_bounds__(256) void k_gemm1z(const float* __restrict__ x,
    const float* __restrict__ W1, const float* __restrict__ b1,
    const float* __restrict__ W2, const float* __restrict__ b2,
    float* __restrict__ z, int N)
{
  __shared__ float smem[2*BK*(BM+4)];           // At | Bs, later overlaid by hs[64][68]
  float (*At)[BM+4] = (float(*)[BM+4])smem;
  float (*Bs)[BN+4] = (float(*)[BN+4])(smem + BK*(BM+4));
  __shared__ float W2s[DH][DL];
  __shared__ float b2s[DL];
  const int tid = threadIdx.x;
  for (int i = tid; i < DH*DL; i += 256) W2s[i>>4][i&15] = W2[i];
  if (tid < DL) b2s[tid] = b2[tid];
  const int tx = tid & 15, ty = tid >> 4;
  const int row0 = blockIdx.x * BM;
  float acc[4][4] = {};
  for (int k0 = 0; k0 < DF; k0 += BK) {
    #pragma unroll
    for (int i = 0; i < 2; ++i) {
      int idx = tid + i*256;
      int r  = idx >> 3;
      int kk = (idx & 7) << 2;
      int row = row0 + r;
      float4 va = make_float4(0.f,0.f,0.f,0.f);
      if (row < N) va = *(const float4*)&x[(size_t)row*DF + k0 + kk];
      At[kk+0][r]=va.x; At[kk+1][r]=va.y; At[kk+2][r]=va.z; At[kk+3][r]=va.w;
      int r2 = idx >> 4;
      int c4 = (idx & 15) << 2;
      float4 vb = *(const float4*)&W1[(size_t)(k0+r2)*DH + c4];
      Bs[r2][c4+0]=vb.x; Bs[r2][c4+1]=vb.y; Bs[r2][c4+2]=vb.z; Bs[r2][c4+3]=vb.w;
    }
    __syncthreads();
    #pragma unroll
    for (int kk = 0; kk < BK; ++kk) {
      float4 av = *(const float4*)&At[kk][ty<<2];
      float4 bv = *(const float4*)&Bs[kk][tx<<2];
      float a4[4]={av.x,av.y,av.z,av.w};
      float b4[4]={bv.x,bv.y,bv.z,bv.w};
      #pragma unroll
      for (int i=0;i<4;++i)
        #pragma unroll
        for (int j=0;j<4;++j) acc[i][j] = fmaf(a4[i], b4[j], acc[i][j]);
    }
    __syncthreads();
  }
  // epilogue: h tile (64 rows x all 64 hidden) -> LDS (overlay At/Bs), then z = h@W2+b2
  float4 bias = ((const float4*)b1)[tx];
  float bias4[4] = {bias.x, bias.y, bias.z, bias.w};
  float (*hs)[BM+4] = (float(*)[BM+4])smem;     // 64 x 68 == 2*(32 x 68)
  #pragma unroll
  for (int i=0;i<4;++i){
    #pragma unroll
    for (int j=0;j<4;++j)
      hs[(ty<<2)+i][(tx<<2)+j] = fmaxf(acc[i][j] + bias4[j], 0.0f);
  }
  __syncthreads();
  int row = tid >> 2, lg = tid & 3;
  float4 zacc = ((const float4*)b2s)[lg];
  #pragma unroll 8
  for (int k = 0; k < DH; ++k){
    float hv = hs[row][k];
    float4 wv = *(const float4*)&W2s[k][lg<<2];
    zacc.x = fmaf(hv, wv.x, zacc.x);
    zacc.y = fmaf(hv, wv.y, zacc.y);
    zacc.z = fmaf(hv, wv.z, zacc.z);
    zacc.w = fmaf(hv, wv.w, zacc.w);
  }
  int grow = row0 + row;
  if (grow < N) ((float4*)z)[(size_t)grow*4 + lg] = zacc;
}

// -------- radial flows: one thread per (node, class) --------
__global__ __launch_bounds__(256) void k_flow2(const float* __restrict__ z,
    const float* __restrict__ pc, const float* __restrict__ z0g,
    const float* __restrict__ apg, const float* __restrict__ fbg,
    float* __restrict__ x0, int N)
{
  __shared__ float z0s[NF][NC][DL];
  __shared__ float alps[NF][NC];
  __shared__ float bhs[NF][NC];
  __shared__ float lpc[NC];
  int tid = threadIdx.x;
  for (int i = tid; i < NF*NC*DL; i += 256)
    z0s[(i>>4)/NC][(i>>4)%NC][i&15] = z0g[i];
  if (tid < NF*NC){
    int l = tid/NC, c = tid%NC;
    float al = softplus_(apg[tid]);
    alps[l][c] = al;
    bhs[l][c]  = -al + softplus_(fbg[tid]);
  }
  if (tid < NC) lpc[tid] = __logf(pc[tid]);
  __syncthreads();

  int idx = blockIdx.x*256 + tid;
  int n = idx >> 4, c = idx & 15;
  if (n >= N) return;
  if (c >= NC){ x0[idx] = 0.f; return; }

  float zz[DL];
  const float4* z4 = (const float4*)z;
  #pragma unroll
  for (int q=0; q<4; ++q){
    float4 v = z4[(size_t)n*4 + q];
    zz[q*4+0]=v.x; zz[q*4+1]=v.y; zz[q*4+2]=v.z; zz[q*4+3]=v.w;
  }
  const float NEGHALFD_LOG2PI = -14.703016531274762f;  // -8*log(2*pi)
  const float LOGSCALE        =  20.248193975754326f;  //  8*log(4*pi)
  float sld = 0.f;
  #pragma unroll 1
  for (int l=0; l<NF; ++l){
    float al = alps[l][c], bhat = bhs[l][c];
    float dz[DL]; float r2 = 0.f;
    #pragma unroll
    for (int d=0; d<DL; ++d){ float t = zz[d] - z0s[l][c][d]; dz[d]=t; r2 = fmaf(t,t,r2); }
    float r  = sqrtf(r2);
    float hh = 1.0f/(al + r);
    float bh = bhat*hh;
    #pragma unroll
    for (int d=0; d<DL; ++d) zz[d] = fmaf(bh, dz[d], zz[d]);
    sld += 15.0f*__logf(1.0f + bh) + __logf(1.0f + bh - bhat*r*hh*hh);
  }
  float q2 = 0.f;
  #pragma unroll
  for (int d=0; d<DL; ++d) q2 = fmaf(zz[d], zz[d], q2);
  float v = -0.5f*q2 + NEGHALFD_LOG2PI + sld + lpc[c] + LOGSCALE;
  v = fminf(fmaxf(v, -30.f), 30.f);
  x0[idx] = __expf(v);
}

// ---------------- bucketed CSR construction ----------------
__global__ __launch_bounds__(256) void k_bhist(const int* __restrict__ dst,
    int* __restrict__ bCnt, int E, int B)
{
  __shared__ int hh[MAXB];
  int tid = threadIdx.x;
  for (int b = tid; b < B; b += 256) hh[b] = 0;
  __syncthreads();
  for (int i = blockIdx.x*256 + tid; i < E; i += gridDim.x*256)
    atomicAdd(&hh[dst[i] >> BSH], 1);
  __syncthreads();
  for (int b = tid; b < B; b += 256) if (hh[b]) atomicAdd(&bCnt[b], hh[b]);
}

__global__ void k_bscan(const int* __restrict__ bCnt, int* __restrict__ bOff, int B){
  if (blockIdx.x==0 && threadIdx.x==0){
    int run = 0;
    for (int b=0;b<B;++b){ bOff[b]=run; run+=bCnt[b]; }
    bOff[B]=run;
  }
}

__global__ __launch_bounds__(256) void k_bscatter(const int* __restrict__ src,
    const int* __restrict__ dst, const int* __restrict__ bOff,
    int* __restrict__ bCur, int* __restrict__ bp, int E, int B)
{
  __shared__ int hc[MAXB];
  __shared__ int hb[MAXB];
  int tid = threadIdx.x;
  int base = blockIdx.x * TILE;
  int lim  = base + TILE; if (lim > E) lim = E;
  for (int b = tid; b < B; b += 256) hc[b] = 0;
  __syncthreads();
  for (int i = base + tid; i < lim; i += 256)
    atomicAdd(&hc[dst[i] >> BSH], 1);
  __syncthreads();
  for (int b = tid; b < B; b += 256){
    int c = hc[b];
    hb[b] = c ? atomicAdd(&bCur[b], c) : 0;
    hc[b] = 0;
  }
  __syncthreads();
  for (int i = base + tid; i < lim; i += 256){
    int d = dst[i];
    int b = d >> BSH;
    int pos = bOff[b] + hb[b] + atomicAdd(&hc[b], 1);
    bp[pos] = (src[i] << BSH) | (d & (BW-1));
  }
}

__global__ __launch_bounds__(256) void k_bdeg(const int* __restrict__ bp,
    const int* __restrict__ bOff, int* __restrict__ deg, int N)
{
  __shared__ int cur[BW];
  int tid = threadIdx.x;
  int b = blockIdx.x;
  if (tid < BW) cur[tid] = 0;
  __syncthreads();
  int s = bOff[b], e = bOff[b+1];
  for (int i = s + tid; i < e; i += 256)
    atomicAdd(&cur[bp[i] & (BW-1)], 1);
  __syncthreads();
  int node = (b << BSH) + tid;
  if (tid < BW && node < N) deg[node] = cur[tid];
}

__global__ void k_dinv(const int* __restrict__ deg, float* __restrict__ dinv, int N){
  int n = blockIdx.x*256 + threadIdx.x;
  if (n < N) dinv[n] = 1.0f / sqrtf((float)(deg[n] + 1));
}

__global__ __launch_bounds__(256) void k_scan_part(const int* __restrict__ deg,
    int* __restrict__ part, int N){
  __shared__ int sd[256];
  int base = blockIdx.x*1024;
  int tid = threadIdx.x;
  int s = 0;
  #pragma unroll
  for (int i=0;i<4;++i){ int idx = base + tid*4 + i; if (idx < N) s += deg[idx]; }
  sd[tid] = s; __syncthreads();
  for (int ofs=128; ofs>0; ofs>>=1){ if (tid<ofs) sd[tid]+=sd[tid+ofs]; __syncthreads(); }
  if (tid==0) part[blockIdx.x] = sd[0];
}

__global__ void k_scan_top(int* part, int nb){
  if (blockIdx.x==0 && threadIdx.x==0){
    int run = 0;
    for (int i=0;i<nb;++i){ int v = part[i]; part[i] = run; run += v; }
  }
}

__global__ __launch_bounds__(256) void k_scan_final(const int* __restrict__ deg,
    const int* __restrict__ part, int* __restrict__ off, int N, int E)
{
  __shared__ int sc[256];
  int base = blockIdx.x*1024;
  int tid = threadIdx.x;
  int v[4]; int s = 0;
  #pragma unroll
  for (int i=0;i<4;++i){ int idx = base + tid*4 + i; v[i] = (idx<N)?deg[idx]:0; s += v[i]; }
  sc[tid] = s; __syncthreads();
  for (int ofs=1; ofs<256; ofs<<=1){
    int t = (tid>=ofs) ? sc[tid-ofs] : 0;
    __syncthreads();
    sc[tid] += t;
    __syncthreads();
  }
  int ex = sc[tid] - s + part[blockIdx.x];
  #pragma unroll
  for (int i=0;i<4;++i){
    int idx = base + tid*4 + i;
    if (idx < N){
      off[idx] = ex;
      if (idx == N-1) off[N] = ex + v[i];
      ex += v[i];
    }
  }
}

__global__ __launch_bounds__(256) void k_place(const int* __restrict__ bp,
    const int* __restrict__ bOff, const int* __restrict__ off,
    const float* __restrict__ dinv, float2* __restrict__ csrw, int N)
{
  __shared__ int cur[BW];
  int tid = threadIdx.x;
  int b = blockIdx.x;
  if (tid < BW) cur[tid] = 0;
  __syncthreads();
  int node0 = b << BSH;
  int s = bOff[b], e = bOff[b+1];
  for (int i = s + tid; i < e; i += 256){
    int v  = bp[i];
    int dl = v & (BW-1);
    int sn = v >> BSH;
    int d  = node0 + dl;
    int p  = off[d] + atomicAdd(&cur[dl], 1);
    csrw[p] = make_float2(__int_as_float(sn), dinv[sn]*dinv[d]);
  }
}

// ---- canonicalize segment order (stable value-rank via shuffles) ----
__global__ __launch_bounds__(256) void k_rank(float2* __restrict__ csrw,
    const int* __restrict__ off, int N)
{
  int wid  = (blockIdx.x*256 + threadIdx.x) >> 6;
  int lane = threadIdx.x & 63;
  if (wid >= N) return;
  int s = off[wid], e = off[wid+1];
  int d = e - s;
  if (d <= 1) return;
  if (d <= 64){
    float2 pv = (lane < d) ? csrw[s+lane] : make_float2(__int_as_float(INT_MAX), 0.f);
    int v = __float_as_int(pv.x);
    int rank = 0;
    for (int j = 0; j < d; ++j){
      int bv = __shfl(v, j);
      rank += (bv < v) || (bv == v && j < lane);
    }
    if (lane < d) csrw[s+rank] = pv;
  } else if (d <= 256){
    float2 p0 = (lane      < d) ? csrw[s+lane      ] : make_float2(__int_as_float(INT_MAX),0.f);
    float2 p1 = (lane+64   < d) ? csrw[s+lane+64   ] : make_float2(__int_as_float(INT_MAX),0.f);
    float2 p2 = (lane+128  < d) ? csrw[s+lane+128  ] : make_float2(__int_as_float(INT_MAX),0.f);
    float2 p3 = (lane+192  < d) ? csrw[s+lane+192  ] : make_float2(__int_as_float(INT_MAX),0.f);
    int v0=__float_as_int(p0.x), v1=__float_as_int(p1.x);
    int v2=__float_as_int(p2.x), v3=__float_as_int(p3.x);
    int r0=0,r1=0,r2=0,r3=0;
    for (int j = 0; j < d; ++j){
      int slot = j >> 6, jl = j & 63;
      int bv = (slot==0) ? __shfl(v0,jl) : (slot==1) ? __shfl(v1,jl)
             : (slot==2) ? __shfl(v2,jl) : __shfl(v3,jl);
      r0 += (bv < v0) || (bv == v0 && j < lane);
      r1 += (bv < v1) || (bv == v1 && j < lane+64);
      r2 += (bv < v2) || (bv == v2 && j < lane+128);
      r3 += (bv < v3) || (bv == v3 && j < lane+192);
    }
    if (lane      < d) csrw[s+r0]=p0;
    if (lane+64   < d) csrw[s+r1]=p1;
    if (lane+128  < d) csrw[s+r2]=p2;
    if (lane+192  < d) csrw[s+r3]=p3;
  } else {
    if (lane == 0){
      for (int i = s+1; i < e; ++i){
        float2 key = csrw[i];
        int kv = __float_as_int(key.x);
        int j = i-1;
        while (j >= s && __float_as_int(csrw[j].x) > kv){ csrw[j+1] = csrw[j]; --j; }
        csrw[j+1] = key;
      }
    }
  }
}

// ---------------- APPNP iteration: 4 threads/node, float4, unroll 4 ----------------
__global__ __launch_bounds__(256) void k_prop(const float* __restrict__ bsrc,
    const float* __restrict__ x0, float* __restrict__ bdst,
    const float2* __restrict__ csrw, const int* __restrict__ off,
    const float* __restrict__ dinv, int N)
{
  int t = blockIdx.x*256 + threadIdx.x;
  int n = t >> 2, q = t & 3;
  if (n >= N) return;
  const float4* b4 = (const float4*)bsrc;
  float dn = dinv[n];
  float4 self = b4[(size_t)n*4 + q];
  float wself = dn*dn;
  float4 a0 = make_float4(wself*self.x, wself*self.y, wself*self.z, wself*self.w);
  float4 a1 = make_float4(0.f,0.f,0.f,0.f);
  float4 a2 = make_float4(0.f,0.f,0.f,0.f);
  float4 a3 = make_float4(0.f,0.f,0.f,0.f);
  int s = off[n], e = off[n+1];
  int i = s;
  for (; i+4 <= e; i += 4){
    float2 p0 = csrw[i], p1 = csrw[i+1], p2 = csrw[i+2], p3 = csrw[i+3];
    float4 v0 = b4[(size_t)__float_as_int(p0.x)*4 + q];
    float4 v1 = b4[(size_t)__float_as_int(p1.x)*4 + q];
    float4 v2 = b4[(size_t)__float_as_int(p2.x)*4 + q];
    float4 v3 = b4[(size_t)__float_as_int(p3.x)*4 + q];
    a0.x = fmaf(p0.y, v0.x, a0.x); a0.y = fmaf(p0.y, v0.y, a0.y);
    a0.z = fmaf(p0.y, v0.z, a0.z); a0.w = fmaf(p0.y, v0.w, a0.w);
    a1.x = fmaf(p1.y, v1.x, a1.x); a1.y = fmaf(p1.y, v1.y, a1.y);
    a1.z = fmaf(p1.y, v1.z, a1.z); a1.w = fmaf(p1.y, v1.w, a1.w);
    a2.x = fmaf(p2.y, v2.x, a2.x); a2.y = fmaf(p2.y, v2.y, a2.y);
    a2.z = fmaf(p2.y, v2.z, a2.z); a2.w = fmaf(p2.y, v2.w, a2.w);
    a3.x = fmaf(p3.y, v3.x, a3.x); a3.y = fmaf(p3.y, v3.y, a3.y);
    a3.z = fmaf(p3.y, v3.z, a3.z); a3.w = fmaf(p3.y, v3.w, a3.w);
  }
  for (; i < e; ++i){
    float2 p0 = csrw[i];
    float4 v0 = b4[(size_t)__float_as_int(p0.x)*4 + q];
    a0.x = fmaf(p0.y, v0.x, a0.x); a0.y = fmaf(p0.y, v0.y, a0.y);
    a0.z = fmaf(p0.y, v0.z, a0.z); a0.w = fmaf(p0.y, v0.w, a0.w);
  }
  float4 xv = ((const float4*)x0)[(size_t)n*4 + q];
  float4 o;
  o.x = fmaf(0.9f, (a0.x+a1.x)+(a2.x+a3.x), 0.1f*xv.x);
  o.y = fmaf(0.9f, (a0.y+a1.y)+(a2.y+a3.y), 0.1f*xv.y);
  o.z = fmaf(0.9f, (a0.z+a1.z)+(a2.z+a3.z), 0.1f*xv.z);
  o.w = fmaf(0.9f, (a0.w+a1.w)+(a2.w+a3.w), 0.1f*xv.w);
  ((float4*)bdst)[(size_t)n*4 + q] = o;
}

// ---- last APPNP iteration fused with alpha/soft/argmax ----
__global__ __launch_bounds__(256) void k_prop_final(const float* __restrict__ bsrc,
    const float* __restrict__ x0,
    const float2* __restrict__ csrw, const int* __restrict__ off,
    const float* __restrict__ dinv, float* __restrict__ out, int N)
{
  int t = blockIdx.x*256 + threadIdx.x;
  int n = t >> 2, q = t & 3;
  if (n >= N) return;
  const float4* b4 = (const float4*)bsrc;
  float dn = dinv[n];
  float4 self = b4[(size_t)n*4 + q];
  float wself = dn*dn;
  float4 a0 = make_float4(wself*self.x, wself*self.y, wself*self.z, wself*self.w);
  float4 a1 = make_float4(0.f,0.f,0.f,0.f);
  float4 a2 = make_float4(0.f,0.f,0.f,0.f);
  float4 a3 = make_float4(0.f,0.f,0.f,0.f);
  int s = off[n], e = off[n+1];
  int i = s;
  for (; i+4 <= e; i += 4){
    float2 p0 = csrw[i], p1 = csrw[i+1], p2 = csrw[i+2], p3 = csrw[i+3];
    float4 v0 = b4[(size_t)__float_as_int(p0.x)*4 + q];
    float4 v1 = b4[(size_t)__float_as_int(p1.x)*4 + q];
    float4 v2 = b4[(size_t)__float_as_int(p2.x)*4 + q];
    float4 v3 = b4[(size_t)__float_as_int(p3.x)*4 + q];
    a0.x = fmaf(p0.y, v0.x, a0.x); a0.y = fmaf(p0.y, v0.y, a0.y);
    a0.z = fmaf(p0.y, v0.z, a0.z); a0.w = fmaf(p0.y, v0.w, a0.w);
    a1.x = fmaf(p1.y, v1.x, a1.x); a1.y = fmaf(p1.y, v1.y, a1.y);
    a1.z = fmaf(p1.y, v1.z, a1.z); a1.w = fmaf(p1.y, v1.w, a1.w);
    a2.x = fmaf(p2.y, v2.x, a2.x); a2.y = fmaf(p2.y, v2.y, a2.y);
    a2.z = fmaf(p2.y, v2.z, a2.z); a2.w = fmaf(p2.y, v2.w, a2.w);
    a3.x = fmaf(p3.y, v3.x, a3.x); a3.y = fmaf(p3.y, v3.y, a3.y);
    a3.z = fmaf(p3.y, v3.z, a3.z); a3.w = fmaf(p3.y, v3.w, a3.w);
  }
  for (; i < e; ++i){
    float2 p0 = csrw[i];
    float4 v0 = b4[(size_t)__float_as_int(p0.x)*4 + q];
    a0.x = fmaf(p0.y, v0.x, a0.x); a0.y = fmaf(p0.y, v0.y, a0.y);
    a0.z = fmaf(p0.y, v0.z, a0.z); a0.w = fmaf(p0.y, v0.w, a0.w);
  }
  float4 xv = ((const float4*)x0)[(size_t)n*4 + q];
  float4 al;
  al.x = fmaf(0.9f, (a0.x+a1.x)+(a2.x+a3.x), fmaf(0.1f, xv.x, 1.f));
  al.y = fmaf(0.9f, (a0.y+a1.y)+(a2.y+a3.y), fmaf(0.1f, xv.y, 1.f));
  al.z = fmaf(0.9f, (a0.z+a1.z)+(a2.z+a3.z), fmaf(0.1f, xv.z, 1.f));
  al.w = fmaf(0.9f, (a0.w+a1.w)+(a2.w+a3.w), fmaf(0.1f, xv.w, 1.f));

  float sv = 0.f;
  if (q < 2)       sv = al.x + al.y + al.z + al.w;
  else if (q == 2) sv = al.x + al.y;
  sv += __shfl_xor(sv, 1, 4);
  sv += __shfl_xor(sv, 2, 4);

  float bv = -1e30f; int bi = 999;
  int cb = q*4;
  int nvalid = (q < 2) ? 4 : (q == 2 ? 2 : 0);
  float av[4] = {al.x, al.y, al.z, al.w};
  for (int j = 0; j < nvalid; ++j){
    if (av[j] > bv){ bv = av[j]; bi = cb + j; }
  }
  #pragma unroll
  for (int o = 1; o <= 2; o <<= 1){
    float vo = __shfl_xor(bv, o, 4);
    int  io  = __shfl_xor(bi, o, 4);
    if (vo > bv || (vo == bv && io < bi)){ bv = vo; bi = io; }
  }

  float inv = 1.0f / sv;
  size_t sb = (size_t)N + (size_t)n*NC;
  for (int j = 0; j < nvalid; ++j) out[sb + cb + j] = av[j] * inv;
  if (q == 0) out[n] = (float)bi;
}

extern "C" void kernel_launch(void* const* d_in, const int* in_sizes, int n_in,
                              void* d_out, int out_size, void* d_ws, size_t ws_size,
                              hipStream_t stream)
{
  const float* x  = (const float*)d_in[0];
  const int*   ei = (const int*)  d_in[1];
  const float* pc = (const float*)d_in[2];
  const float* W1 = (const float*)d_in[3];
  const float* b1 = (const float*)d_in[4];
  const float* W2 = (const float*)d_in[5];
  const float* b2 = (const float*)d_in[6];
  const float* z0 = (const float*)d_in[7];
  const float* ap = (const float*)d_in[8];
  const float* fb = (const float*)d_in[9];
  float* out = (float*)d_out;

  const int N = in_sizes[0] / DF;
  const int E = in_sizes[1] / 2;
  const int* src = ei;
  const int* dst = ei + E;
  const int B = (N + BW - 1) >> BSH;

  // Workspace. region0 holds z (N*16 f32) during phase 1, then bp (E ints)
  // during CSR build (z is dead after k_flow2).
  char* ws = (char*)d_ws;
  size_t o = 0;
  size_t region0 = (size_t)N*DL*sizeof(float);
  if ((size_t)E*sizeof(int) > region0) region0 = (size_t)E*sizeof(int);
  float* z    = (float*)(ws + o);
  int*   bp   = (int*)  (ws + o);
  o += region0;
  float2* csrw = (float2*)(ws + o); o += (size_t)E*sizeof(float2);
  float* x0   = (float*)(ws + o); o += (size_t)N*DL*sizeof(float);
  float* bA   = (float*)(ws + o); o += (size_t)N*DL*sizeof(float);
  float* bB   = (float*)(ws + o); o += (size_t)N*DL*sizeof(float);
  int*   deg  = (int*)  (ws + o); o += (size_t)N*sizeof(int);
  float* dinv = (float*)(ws + o); o += (size_t)N*sizeof(float);
  int*   offs = (int*)  (ws + o); o += (size_t)(N+2)*sizeof(int);
  int*   part = (int*)  (ws + o); o += 4096;
  int*   bCnt = (int*)  (ws + o); o += MAXB*sizeof(int);
  int*   bOff = (int*)  (ws + o); o += (MAXB+1)*sizeof(int);
  int*   bCur = (int*)  (ws + o); o += MAXB*sizeof(int);

  const int TB = 256;
  int gN  = (N + TB - 1) / TB;
  int nb  = (N + 1023) / 1024;

  // Phase 1: encoder fused with z projection, then flows -> x0
  k_gemm1z<<<(N + BM - 1) / BM, TB, 0, stream>>>(x, W1, b1, W2, b2, z, N);
  k_flow2<<<((N*DL) + TB - 1) / TB, TB, 0, stream>>>(z, pc, z0, ap, fb, x0, N);

  // Phase 2: bucketed CSR build (reuses z region for bp)
  hipMemsetAsync(bCnt, 0, MAXB*sizeof(int), stream);
  hipMemsetAsync(bCur, 0, MAXB*sizeof(int), stream);
  k_bhist<<<512, TB, 0, stream>>>(dst, bCnt, E, B);
  k_bscan<<<1, 1, 0, stream>>>(bCnt, bOff, B);
  k_bscatter<<<(E + TILE - 1)/TILE, TB, 0, stream>>>(src, dst, bOff, bCur, bp, E, B);
  k_bdeg<<<B, TB, 0, stream>>>(bp, bOff, deg, N);
  k_dinv<<<gN, TB, 0, stream>>>(deg, dinv, N);
  k_scan_part<<<nb, TB, 0, stream>>>(deg, part, N);
  k_scan_top<<<1, 1, 0, stream>>>(part, nb);
  k_scan_final<<<nb, TB, 0, stream>>>(deg, part, offs, N, E);
  k_place<<<B, TB, 0, stream>>>(bp, bOff, offs, dinv, csrw, N);
  k_rank<<<(N + 3) / 4, TB, 0, stream>>>(csrw, offs, N);

  // Phase 3: APPNP — 9 plain iterations + 1 fused with the epilogue
  int gP = ((N*4) + TB - 1) / TB;
  const float* bin = x0;
  for (int it = 0; it < KPROP-1; ++it){
    float* bout = (it & 1) ? bB : bA;
    k_prop<<<gP, TB, 0, stream>>>(bin, x0, bout, csrw, offs, dinv, N);
    bin = bout;
  }
  k_prop_final<<<gP, TB, 0, stream>>>(bin, x0, csrw, offs, dinv, out, N);
}